// Round 3
// baseline (151.141 us; speedup 1.0000x reference)
//
#include <hip/hip_runtime.h>
#include <math.h>

#define BB 512
#define DD 128
#define KK 8
#define BOUNDARY 4

// ---------------- workspace layout (bytes) ----------------
// d      : 0        .. 1048576   (512*512 float)   row i written by block i
// posIdx : 1048576  .. 1064960   (512*8 int)       top-8 pos rows per column, -1 fill
// negIdx : 1064960  .. 1081344   (512*8 int)
// anchor : 1081344  .. 1083392   (512 int)
// partS  : 1083392  .. 1085440   (512 float)
// partC  : 1085440  .. 1087488   (512 int)
// All regions written unconditionally before read -> no memset needed.

// One wave per row/column i. d is bitwise symmetric (same accumulation order
// everywhere), so row i == column i. Computes distances, stores the row,
// then does top-k (jax.lax.top_k order: descending value, lower index on tie)
// via argmax-with-removal, plus the minor-class anchor flag.
__global__ void dist_topk_kernel(const float* __restrict__ x, const int* __restrict__ tgt,
                                 float* __restrict__ d,
                                 int* __restrict__ posIdx, int* __restrict__ negIdx,
                                 int* __restrict__ anchor) {
    __shared__ float4 xi4[DD / 4];
    int i = blockIdx.x;
    int lane = threadIdx.x;          // 0..63
    if (lane < DD / 4) xi4[lane] = ((const float4*)(x + i * DD))[lane];
    __syncthreads();
    int ti = tgt[i];

    // sqi: same sequential order as reference-replicating scalar loop
    float sqi = 0.f;
    for (int c = 0; c < DD / 4; ++c) {
        float4 a = xi4[c];
        sqi += a.x * a.x; sqi += a.y * a.y; sqi += a.z * a.z; sqi += a.w * a.w;
    }

    float vp[8], vn[8];
    int samecnt = 0;
    for (int q = 0; q < 8; ++q) {
        int r = q * 64 + lane;
        const float4* xr = (const float4*)(x + r * DD);
        float dot = 0.f, sqr = 0.f;
        for (int c = 0; c < DD / 4; ++c) {
            float4 a = xi4[c], b = xr[c];
            dot += a.x * b.x; dot += a.y * b.y; dot += a.z * b.z; dot += a.w * b.w;
            sqr += b.x * b.x; sqr += b.y * b.y; sqr += b.z * b.z; sqr += b.w * b.w;
        }
        float dsq = fmaxf(sqi + sqr - 2.f * dot, 0.f);
        float dv = (dsq == 0.f) ? 0.f : sqrtf(dsq);
        d[i * BB + r] = dv;
        bool same = (tgt[r] == ti);
        samecnt += same ? 1 : 0;
        vp[q] = same ? dv : -INFINITY;
        vn[q] = same ? -INFINITY : -dv;
    }

    // anchor flag: class count (includes self) < boundary
    int sc = samecnt;
    for (int off = 32; off > 0; off >>= 1) sc += __shfl_down(sc, off);
    if (lane == 0) anchor[i] = (sc < BOUNDARY) ? 1 : 0;

    // hard positives (same-class, largest d)
    {
        int written = 0;
        for (int pass = 0; pass < KK; ++pass) {
            float bv = -INFINITY; int bq = -1;
            for (int q = 0; q < 8; ++q)
                if (vp[q] > bv) { bv = vp[q]; bq = q; }
            int bi = (bq >= 0) ? (bq * 64 + lane) : (1 << 30);
            for (int off = 32; off > 0; off >>= 1) {
                float ov = __shfl_down(bv, off);
                int   oi = __shfl_down(bi, off);
                if (ov > bv || (ov == bv && oi < bi)) { bv = ov; bi = oi; }
            }
            bv = __shfl(bv, 0); bi = __shfl(bi, 0);
            if (bv == -INFINITY) break;
            if (lane == 0) posIdx[i * KK + pass] = bi;
            written = pass + 1;
            if ((bi & 63) == lane) vp[bi >> 6] = -INFINITY;
        }
        if (lane == 0)
            for (int p = written; p < KK; ++p) posIdx[i * KK + p] = -1;
    }
    // hard negatives (different-class, smallest d == largest -d)
    {
        int written = 0;
        for (int pass = 0; pass < KK; ++pass) {
            float bv = -INFINITY; int bq = -1;
            for (int q = 0; q < 8; ++q)
                if (vn[q] > bv) { bv = vn[q]; bq = q; }
            int bi = (bq >= 0) ? (bq * 64 + lane) : (1 << 30);
            for (int off = 32; off > 0; off >>= 1) {
                float ov = __shfl_down(bv, off);
                int   oi = __shfl_down(bi, off);
                if (ov > bv || (ov == bv && oi < bi)) { bv = ov; bi = oi; }
            }
            bv = __shfl(bv, 0); bi = __shfl(bi, 0);
            if (bv == -INFINITY) break;
            if (lane == 0) negIdx[i * KK + pass] = bi;
            written = pass + 1;
            if ((bi & 63) == lane) vn[bi >> 6] = -INFINITY;
        }
        if (lane == 0)
            for (int p = written; p < KK; ++p) negIdx[i * KK + p] = -1;
    }
}

__global__ void loss_kernel(const float* __restrict__ d,
                            const int* __restrict__ posIdx, const int* __restrict__ negIdx,
                            const int* __restrict__ anchor,
                            float* __restrict__ partS, int* __restrict__ partC) {
    int i = blockIdx.x;
    __shared__ int pos[BB];
    __shared__ int neg[BB];
    __shared__ int np_s, nn_s;
    __shared__ float sred[256];
    __shared__ int   cred[256];
    if (!anchor[i]) {
        if (threadIdx.x == 0) { partS[i] = 0.f; partC[i] = 0; }
        return;
    }
    if (threadIdx.x == 0) { np_s = 0; nn_s = 0; }
    __syncthreads();
    for (int j = threadIdx.x; j < BB; j += blockDim.x) {
        const int* pj = posIdx + j * KK;
        bool hit = false;
        for (int s = 0; s < KK; ++s) hit |= (pj[s] == i);
        if (hit && j != i) pos[atomicAdd(&np_s, 1)] = j;
        const int* nj = negIdx + j * KK;
        hit = false;
        for (int s = 0; s < KK; ++s) hit |= (nj[s] == i);
        if (hit) neg[atomicAdd(&nn_s, 1)] = j;
    }
    __syncthreads();
    int np = np_s, nn = nn_s;
    int tot = np * nn;
    float s = 0.f; int c = 0;
    const float* di = d + i * BB;
    for (int t = threadIdx.x; t < tot; t += blockDim.x) {
        float tv = di[pos[t / nn]] - di[neg[t % nn]] + 1.0f;
        if (tv > 0.f) {
            s += tv;
            if (tv > 1e-7f) c += 1;
        }
    }
    sred[threadIdx.x] = s; cred[threadIdx.x] = c;
    __syncthreads();
    for (int off = 128; off > 0; off >>= 1) {
        if (threadIdx.x < off) {
            sred[threadIdx.x] += sred[threadIdx.x + off];
            cred[threadIdx.x] += cred[threadIdx.x + off];
        }
        __syncthreads();
    }
    if (threadIdx.x == 0) { partS[i] = sred[0]; partC[i] = cred[0]; }
}

__global__ void fin_kernel(const float* __restrict__ partS, const int* __restrict__ partC,
                           float* __restrict__ out) {
    __shared__ float sred[256];
    __shared__ int   cred[256];
    int t = threadIdx.x;
    sred[t] = partS[t] + partS[t + 256];
    cred[t] = partC[t] + partC[t + 256];
    __syncthreads();
    for (int off = 128; off > 0; off >>= 1) {
        if (t < off) { sred[t] += sred[t + off]; cred[t] += cred[t + off]; }
        __syncthreads();
    }
    if (t == 0) out[0] = sred[0] / ((float)cred[0] + 1e-7f);
}

extern "C" void kernel_launch(void* const* d_in, const int* in_sizes, int n_in,
                              void* d_out, int out_size, void* d_ws, size_t ws_size,
                              hipStream_t stream) {
    const float* x   = (const float*)d_in[0];
    const int*   tgt = (const int*)d_in[1];
    float* out = (float*)d_out;

    char* ws = (char*)d_ws;
    float* dmat   = (float*)(ws + 0);
    int*   posIdx = (int*)(ws + 1048576);
    int*   negIdx = (int*)(ws + 1064960);
    int*   anchor = (int*)(ws + 1081344);
    float* partS  = (float*)(ws + 1083392);
    int*   partC  = (int*)(ws + 1085440);

    dist_topk_kernel<<<BB, 64, 0, stream>>>(x, tgt, dmat, posIdx, negIdx, anchor);
    loss_kernel<<<BB, 256, 0, stream>>>(dmat, posIdx, negIdx, anchor, partS, partC);
    fin_kernel<<<1, 256, 0, stream>>>(partS, partC, out);
}

// Round 4
// 94.275 us; speedup vs baseline: 1.6032x; 1.6032x over previous
//
#include <hip/hip_runtime.h>
#include <math.h>

#define BB 512
#define DD 128
#define KK 8
#define BOUNDARY 4

// ---------------- workspace layout (bytes) ----------------
// d      : 0        .. 1048576   (512*512 float)   row i written by block i
// posIdx : 1048576  .. 1064960   (512*8 int)       top-8 pos rows per column, -1 fill
// negIdx : 1064960  .. 1081344   (512*8 int)
// anchor : 1081344  .. 1083392   (512 int)
// partS  : 1083392  .. 1085440   (512 float)
// partC  : 1085440  .. 1087488   (512 int)
// All regions written unconditionally before read -> no memset needed.

// Block i (256 threads): compute row i of the (symmetric) distance matrix with
// 8 independent accumulator chains per row (2 rows/thread), stage masked values
// in LDS, then wave0 = pos top-k, wave1 = neg top-k (in parallel), wave2 =
// anchor flag. Top-k order matches jax.lax.top_k: descending value, lower
// index on tie. Diagonal is exactly 0: sqi, sqr and dot for r==i use the
// identical op sequence, so sqi+sqr-2*dot == v+v-2v == 0 in fp32.
__global__ __launch_bounds__(256) void dist_topk_kernel(
    const float* __restrict__ x, const int* __restrict__ tgt,
    float* __restrict__ d,
    int* __restrict__ posIdx, int* __restrict__ negIdx,
    int* __restrict__ anchor)
{
    __shared__ float4 xi4[DD / 4];
    __shared__ float s_vp[BB];
    __shared__ float s_vn[BB];
    int i = blockIdx.x;
    int t = threadIdx.x;
    if (t < DD / 4) xi4[t] = ((const float4*)(x + i * DD))[t];
    __syncthreads();
    int ti = tgt[i];

    // sqi with the same 4-chain structure used for sqr below
    float q0 = 0.f, q1 = 0.f, q2 = 0.f, q3 = 0.f;
    for (int c = 0; c < DD / 4; ++c) {
        float4 a = xi4[c];
        q0 += a.x * a.x; q1 += a.y * a.y; q2 += a.z * a.z; q3 += a.w * a.w;
    }
    float sqi = (q0 + q1) + (q2 + q3);

    for (int rr = 0; rr < 2; ++rr) {
        int r = t + rr * 256;
        const float4* xr = (const float4*)(x + r * DD);
        float d0 = 0.f, d1 = 0.f, d2 = 0.f, d3 = 0.f;
        float s0 = 0.f, s1 = 0.f, s2 = 0.f, s3 = 0.f;
        for (int c = 0; c < DD / 4; ++c) {
            float4 a = xi4[c], b = xr[c];
            d0 += a.x * b.x; d1 += a.y * b.y; d2 += a.z * b.z; d3 += a.w * b.w;
            s0 += b.x * b.x; s1 += b.y * b.y; s2 += b.z * b.z; s3 += b.w * b.w;
        }
        float dot = (d0 + d1) + (d2 + d3);
        float sqr = (s0 + s1) + (s2 + s3);
        float dsq = fmaxf((sqi + sqr) - 2.f * dot, 0.f);
        float dv = (dsq == 0.f) ? 0.f : sqrtf(dsq);
        d[i * BB + r] = dv;                       // coalesced
        bool same = (tgt[r] == ti);
        s_vp[r] = same ? dv : -INFINITY;
        s_vn[r] = same ? -INFINITY : -dv;
    }
    __syncthreads();

    int wave = t >> 6, lane = t & 63;
    if (wave == 0) {
        // hard positives: top-8 largest same-class distances
        float v[8];
        for (int q = 0; q < 8; ++q) v[q] = s_vp[q * 64 + lane];
        int written = 0;
        for (int pass = 0; pass < KK; ++pass) {
            float bv = -INFINITY; int bq = -1;
            for (int q = 0; q < 8; ++q)
                if (v[q] > bv) { bv = v[q]; bq = q; }   // strict > keeps lowest q
            int bi = (bq >= 0) ? (bq * 64 + lane) : (1 << 30);
            for (int off = 32; off > 0; off >>= 1) {
                float ov = __shfl_down(bv, off);
                int   oi = __shfl_down(bi, off);
                if (ov > bv || (ov == bv && oi < bi)) { bv = ov; bi = oi; }
            }
            bv = __shfl(bv, 0); bi = __shfl(bi, 0);
            if (bv == -INFINITY) break;
            if (lane == 0) posIdx[i * KK + pass] = bi;
            written = pass + 1;
            if ((bi & 63) == lane) v[bi >> 6] = -INFINITY;
        }
        if (lane == 0)
            for (int p = written; p < KK; ++p) posIdx[i * KK + p] = -1;
    } else if (wave == 1) {
        // hard negatives: top-8 largest -d among different-class rows
        float v[8];
        for (int q = 0; q < 8; ++q) v[q] = s_vn[q * 64 + lane];
        int written = 0;
        for (int pass = 0; pass < KK; ++pass) {
            float bv = -INFINITY; int bq = -1;
            for (int q = 0; q < 8; ++q)
                if (v[q] > bv) { bv = v[q]; bq = q; }
            int bi = (bq >= 0) ? (bq * 64 + lane) : (1 << 30);
            for (int off = 32; off > 0; off >>= 1) {
                float ov = __shfl_down(bv, off);
                int   oi = __shfl_down(bi, off);
                if (ov > bv || (ov == bv && oi < bi)) { bv = ov; bi = oi; }
            }
            bv = __shfl(bv, 0); bi = __shfl(bi, 0);
            if (bv == -INFINITY) break;
            if (lane == 0) negIdx[i * KK + pass] = bi;
            written = pass + 1;
            if ((bi & 63) == lane) v[bi >> 6] = -INFINITY;
        }
        if (lane == 0)
            for (int p = written; p < KK; ++p) negIdx[i * KK + p] = -1;
    } else if (wave == 2) {
        // anchor flag: same-class count (incl. self) < boundary
        int cnt = 0;
        for (int q = 0; q < 8; ++q)
            cnt += (s_vp[q * 64 + lane] != -INFINITY) ? 1 : 0;
        for (int off = 32; off > 0; off >>= 1) cnt += __shfl_down(cnt, off);
        if (lane == 0) anchor[i] = (cnt < BOUNDARY) ? 1 : 0;
    }
}

__global__ void loss_kernel(const float* __restrict__ d,
                            const int* __restrict__ posIdx, const int* __restrict__ negIdx,
                            const int* __restrict__ anchor,
                            float* __restrict__ partS, int* __restrict__ partC) {
    int i = blockIdx.x;
    __shared__ int pos[BB];
    __shared__ int neg[BB];
    __shared__ int np_s, nn_s;
    __shared__ float sred[256];
    __shared__ int   cred[256];
    if (!anchor[i]) {
        if (threadIdx.x == 0) { partS[i] = 0.f; partC[i] = 0; }
        return;
    }
    if (threadIdx.x == 0) { np_s = 0; nn_s = 0; }
    __syncthreads();
    for (int j = threadIdx.x; j < BB; j += blockDim.x) {
        const int* pj = posIdx + j * KK;
        bool hit = false;
        for (int s = 0; s < KK; ++s) hit |= (pj[s] == i);
        if (hit && j != i) pos[atomicAdd(&np_s, 1)] = j;
        const int* nj = negIdx + j * KK;
        hit = false;
        for (int s = 0; s < KK; ++s) hit |= (nj[s] == i);
        if (hit) neg[atomicAdd(&nn_s, 1)] = j;
    }
    __syncthreads();
    int np = np_s, nn = nn_s;
    int tot = np * nn;
    float s = 0.f; int c = 0;
    const float* di = d + i * BB;
    for (int t = threadIdx.x; t < tot; t += blockDim.x) {
        float tv = di[pos[t / nn]] - di[neg[t % nn]] + 1.0f;
        if (tv > 0.f) {
            s += tv;
            if (tv > 1e-7f) c += 1;
        }
    }
    sred[threadIdx.x] = s; cred[threadIdx.x] = c;
    __syncthreads();
    for (int off = 128; off > 0; off >>= 1) {
        if (threadIdx.x < off) {
            sred[threadIdx.x] += sred[threadIdx.x + off];
            cred[threadIdx.x] += cred[threadIdx.x + off];
        }
        __syncthreads();
    }
    if (threadIdx.x == 0) { partS[i] = sred[0]; partC[i] = cred[0]; }
}

__global__ void fin_kernel(const float* __restrict__ partS, const int* __restrict__ partC,
                           float* __restrict__ out) {
    __shared__ float sred[256];
    __shared__ int   cred[256];
    int t = threadIdx.x;
    sred[t] = partS[t] + partS[t + 256];
    cred[t] = partC[t] + partC[t + 256];
    __syncthreads();
    for (int off = 128; off > 0; off >>= 1) {
        if (t < off) { sred[t] += sred[t + off]; cred[t] += cred[t + off]; }
        __syncthreads();
    }
    if (t == 0) out[0] = sred[0] / ((float)cred[0] + 1e-7f);
}

extern "C" void kernel_launch(void* const* d_in, const int* in_sizes, int n_in,
                              void* d_out, int out_size, void* d_ws, size_t ws_size,
                              hipStream_t stream) {
    const float* x   = (const float*)d_in[0];
    const int*   tgt = (const int*)d_in[1];
    float* out = (float*)d_out;

    char* ws = (char*)d_ws;
    float* dmat   = (float*)(ws + 0);
    int*   posIdx = (int*)(ws + 1048576);
    int*   negIdx = (int*)(ws + 1064960);
    int*   anchor = (int*)(ws + 1081344);
    float* partS  = (float*)(ws + 1083392);
    int*   partC  = (int*)(ws + 1085440);

    dist_topk_kernel<<<BB, 256, 0, stream>>>(x, tgt, dmat, posIdx, negIdx, anchor);
    loss_kernel<<<BB, 256, 0, stream>>>(dmat, posIdx, negIdx, anchor, partS, partC);
    fin_kernel<<<1, 256, 0, stream>>>(partS, partC, out);
}